// Round 15
// baseline (138.790 us; speedup 1.0000x reference)
//
#include <hip/hip_runtime.h>
#include <hip/hip_fp16.h>

#define BB 4
#define CC 3
#define HH 384
#define WW 384
#define HW (HH * WW)
#define NP (BB * HW)
#define KK 5
#define RR 2
#define K2 25
#define NITER 20
#define TTR 16           // output tile rows
#define TTC 48           // output tile cols
#define KF 4             // fused iterations per launch (5 x 4 = 20)
#define LR 36            // LDS rows: region 32 + 2+2 zero ring
#define RSTH 80          // LDS row stride in HALVES (160 B)
#define NTH 512          // 32 rows x 16 chunks x 4 px = 2048 px region, all active
#define IGRID 768        // (384/16) x (384/48) x 4 = 768 blocks -> 2/CU resident
#define CPX (IGRID / 8)
#define PGRID 1152
#define PCPX (PGRID / 8)
#define GUARDH 1024      // guard halves before planes (max back-reach 770)

static constexpr float INV_Z2 = 1.0f / (0.15f * 0.15f);

typedef _Float16 h2_t __attribute__((ext_vector_type(2)));

#if defined(__has_builtin)
#if __has_builtin(__builtin_amdgcn_fdot2)
#define USE_FDOT2 1
#endif
#endif

static __device__ __forceinline__ unsigned h2u(__half2 h) {
    union { __half2 h; unsigned u; } v; v.h = h; return v.u;
}
#ifdef USE_FDOT2
static __device__ __forceinline__ float fdot2f(unsigned w, unsigned x, float c) {
    union { unsigned u; h2_t h; } a, b; a.u = w; b.u = x;
    return __builtin_amdgcn_fdot2(a.h, b.h, c, false);
}
#endif

// ---------------------------------------------------------------------------
// R14 (128us) diagnosis: iter4 ~15us/launch but throughput arithmetic only
// explains ~6-8 -- and fdot2 (fewer VALU) barely moved it while shrink-region
// (less work) did. Untested residual: IGRID=256 = exactly 1 16-wave block/CU,
// so all 4 barriers, W-load L2 latency, and ramp are serially EXPOSED (no
// co-resident block to overlap). R15 probe: tile 16x48 -> region 32x64 =
// 512 thr x 4 px (all lanes active), 768 blocks of 8 waves -> 2 blocks/CU
// co-resident (VGPR<=128, LDS 11.5KBx2). Cost: redundancy 1.78->2.67
// (~1.24x throughput work). Same fdot2/early-issue/shrink machinery.
// If total <=112: exposure theory confirmed. If >=135: throughput-bound,
// revert to R14 geometry and declare the floor.
// ---------------------------------------------------------------------------

// prep: 2 px/thread. a(p,q) exactly symmetric in fp; center tap exactly 1.
// Stores 12 lex-positive UNnormalized planes (fp16, OOB taps exactly 0),
// invm = mask/sumz (fp32), and x0 = feat*mask. Clamped float2 windows.
__global__ __launch_bounds__(256) void prep_sym(
    const float* __restrict__ img, const float* __restrict__ feat,
    const float* __restrict__ mask, __half* __restrict__ planes,
    float* __restrict__ invm, float* __restrict__ x0)
{
    int sbid = (blockIdx.x & 7) * PCPX + (blockIdx.x >> 3);  // XCD-chunked
    int gid = sbid * 256 + threadIdx.x;
    int p0 = gid * 2;
    int b   = p0 / HW;
    int rem = p0 - b * HW;          // even
    int h   = rem / WW;
    int wc  = rem - h * WW;

    const float* imgb = img + (size_t)b * CC * HW;
    const size_t bHW = (size_t)b * HW;

    float2 f  = *(const float2*)(feat + bHW + rem);
    float2 mk = *(const float2*)(mask + bHW + rem);
    *(float2*)(x0 + bHW + rem) = make_float2(f.x * mk.x, f.y * mk.y);

    float v[CC][2];
#pragma unroll
    for (int c = 0; c < CC; ++c) {
        float2 cv = *(const float2*)(imgb + c * HW + rem);
        v[c][0] = cv.x + 10.f;
        v[c][1] = cv.y + 10.f;
    }

    float sz[2] = {1e-10f, 1e-10f};
#pragma unroll
    for (int dr = 0; dr < KK; ++dr) {
        const int rr  = h + dr - RR;
        const bool rok = (unsigned)rr < HH;
        const int rrc = min(max(rr, 0), HH - 1);
        float xs[CC][6];
#pragma unroll
        for (int c = 0; c < CC; ++c) {
            const float* rowp = imgb + c * HW + rrc * WW;
            float2 A = *(const float2*)(rowp + max(wc - 2, 0));
            float2 Bv = *(const float2*)(rowp + wc);
            float2 Cv = *(const float2*)(rowp + min(wc + 2, WW - 2));
            xs[c][0] = A.x + 10.f;  xs[c][1] = A.y + 10.f;
            xs[c][2] = Bv.x + 10.f; xs[c][3] = Bv.y + 10.f;
            xs[c][4] = Cv.x + 10.f; xs[c][5] = Cv.y + 10.f;
        }
#pragma unroll
        for (int dc = 0; dc < KK; ++dc) {
            const int t = dr * KK + dc;
            float av[2];
#pragma unroll
            for (int s = 0; s < 2; ++s) {
                const int cc2 = wc + s + dc - RR;
                const bool ok = rok && ((unsigned)cc2 < WW);
                float d0 = xs[0][s + dc] - v[0][s];
                float d1 = xs[1][s + dc] - v[1][s];
                float d2 = xs[2][s + dc] - v[2][s];
                float e = d0 * d0 + d1 * d1 + d2 * d2;
                av[s] = ok ? __expf(-e * INV_Z2) : 0.f;
                sz[s] += av[s];
            }
            if (t >= 13) {
                __half2 hv = __floats2half2_rn(av[0], av[1]);
                *(__half2*)(planes + (size_t)(t - 13) * NP + bHW + rem) = hv;
            }
        }
    }
    float i0 = 1.f / sz[0], i1 = 1.f / sz[1];
    *(float2*)(invm + bHW + rem) = make_float2(mk.x * i0, mk.y * i1);
}

// ---------------------------------------------------------------------------
// One launch = KF=4 sub-iterations over a 16x48 tile (region 32x64, 512 thr
// x 4 px, all active). W loaded once (own taps early-issued uint2, mirror
// taps shifted-read + NaN-safe select), packed for v_dot2_f32_f16. x in half
// LDS, dbuf. Shrink-region: sub-iter j guards radius 6-2j (creep-verified).
// ---------------------------------------------------------------------------
__global__ __launch_bounds__(NTH, 2) void iter4(
    const __half* __restrict__ planes, const float* __restrict__ invm,
    const float* __restrict__ xin, float* __restrict__ xout)
{
    __shared__ __half buf[2][LR][RSTH];   // 11.5 KB

    const int tid = threadIdx.x;
    const int lin = (blockIdx.x & 7) * CPX + (blockIdx.x >> 3);  // bijective
    const int b   = lin / 192;            // 24*8 tiles per batch
    const int rem192 = lin - b * 192;
    const int ty  = rem192 >> 3;          // 0..23 (row tile)
    const int tx  = rem192 & 7;           // 0..7  (col tile)
    const int tr0 = ty * TTR, tc0 = tx * TTC;
    const size_t bHW = (size_t)b * HW;

    const int row    = tid >> 4;          // 0..31
    const int chunk  = tid & 15;          // 0..15
    const int relrow = row - 8;           // -8..23
    const int relc0  = chunk * 4 - 8;     // -8..52, multiple of 4
    const int grow = tr0 + relrow;
    const int gcol = tc0 + relc0;
    const bool inimg = ((unsigned)grow < HH) && ((unsigned)gcol <= (WW - 4));
    const int lrow = relrow + 10;         // 2..33
    const int hc   = relc0 + 12;          // 4..64 halves (mult of 4, 8B-align)

    // ---- early-issue independent global loads (latency hides under zero) --
    uint2 own[12];
    float4 xv = make_float4(0.f, 0.f, 0.f, 0.f);
    float4 iv = make_float4(0.f, 0.f, 0.f, 0.f);
    const __half* plb = planes + bHW + (size_t)grow * WW + gcol;
    if (inimg) {
        const size_t off = bHW + (size_t)grow * WW + gcol;
        xv = *(const float4*)(xin + off);
        iv = *(const float4*)(invm + off);
#pragma unroll
        for (int u = 13; u < K2; ++u)
            own[u - 13] = *(const uint2*)(plb + (size_t)(u - 13) * NP);
    }

    // ---- zero both buffers (ring cells never rewritten) -------------------
    for (int i = tid; i < LR * RSTH; i += NTH)
        ((unsigned*)buf)[i] = 0u;
    __syncthreads();

    // stage own x (fp32 -> half LDS)
    {
        union { uint2 u; __half2 h[2]; } st;
        st.h[0] = __floats2half2_rn(xv.x, xv.y);
        st.h[1] = __floats2half2_rn(xv.z, xv.w);
        *(uint2*)&buf[0][lrow][hc] = st.u;
    }

    // ---- mirror loads + W build (overlaps the barrier) --------------------
    __half2 W[K2][2];
    const __half hz = __float2half(0.f);
    if (inimg) {
        W[12][0] = __floats2half2_rn(1.f, 1.f);
        W[12][1] = __floats2half2_rn(1.f, 1.f);
#pragma unroll
        for (int u = 13; u < K2; ++u) {
            const int dur = u / KK - RR;     // 0..2
            const int duc = u % KK - RR;     // -2..2
            const __half* pl = plb + (size_t)(u - 13) * NP;
            union { uint2 u2; __half2 h[2]; } ow;
            ow.u2 = own[u - 13];
            W[u][0] = ow.h[0];
            W[u][1] = ow.h[1];
            const int shift = -(dur * WW + duc);
            const bool okr = (dur == 0) || (grow >= dur);
            __half m[4];
            if ((u % KK) % 2 == 0) {         // duc even: 4B-aligned pair loads
                union { unsigned u32; __half h[2]; } a0, a1;
                a0.u32 = *(const unsigned*)(pl + shift);
                a1.u32 = *(const unsigned*)(pl + shift + 2);
                m[0] = a0.h[0]; m[1] = a0.h[1];
                m[2] = a1.h[0]; m[3] = a1.h[1];
            } else {                          // duc odd: scalar halves
                m[0] = pl[shift + 0]; m[1] = pl[shift + 1];
                m[2] = pl[shift + 2]; m[3] = pl[shift + 3];
            }
#pragma unroll
            for (int k = 0; k < 4; ++k)
                if (!(okr && (unsigned)(gcol + k - duc) < WW)) m[k] = hz;
            W[24 - u][0] = __halves2half2(m[0], m[1]);
            W[24 - u][1] = __halves2half2(m[2], m[3]);
        }
    } else {
#pragma unroll
        for (int t = 0; t < K2; ++t) {
            W[t][0] = __halves2half2(hz, hz);
            W[t][1] = __halves2half2(hz, hz);
        }
    }

#ifdef USE_FDOT2
    // ---- pack W into tap-pair u32s: Wp[px][dr][{dc01,dc23,dc4+zero}] ------
    unsigned Wp[4][KK][3];
#pragma unroll
    for (int dr = 0; dr < KK; ++dr) {
#pragma unroll
        for (int pc = 0; pc < 2; ++pc) {
            const int t0 = dr * KK + 2 * pc;
            unsigned a0 = h2u(W[t0][0]),     b0 = h2u(W[t0][1]);
            unsigned a1 = h2u(W[t0 + 1][0]), b1 = h2u(W[t0 + 1][1]);
            Wp[0][dr][pc] = (a0 & 0xFFFFu) | (a1 << 16);
            Wp[1][dr][pc] = (a0 >> 16)     | (a1 & 0xFFFF0000u);
            Wp[2][dr][pc] = (b0 & 0xFFFFu) | (b1 << 16);
            Wp[3][dr][pc] = (b0 >> 16)     | (b1 & 0xFFFF0000u);
        }
        unsigned a = h2u(W[dr * KK + 4][0]), bb = h2u(W[dr * KK + 4][1]);
        Wp[0][dr][2] = a & 0xFFFFu;
        Wp[1][dr][2] = a >> 16;
        Wp[2][dr][2] = bb & 0xFFFFu;
        Wp[3][dr][2] = bb >> 16;
    }
#endif
    __syncthreads();   // buf[0] fully staged

    // ---- KF sub-iterations, shrink-region guarded -------------------------
    int cur = 0;
    float o[4] = {0.f, 0.f, 0.f, 0.f};
#pragma unroll 1
    for (int j = 0; j < KF; ++j) {
        const int rj = 2 * (KF - 1 - j);            // 6,4,2,0
        const bool actj = (relrow >= -rj) && (relrow < TTR + rj) &&
                          (relc0 + 3 >= -rj) && (relc0 < TTC + rj);
        if (actj) {
            float acc[4] = {0.f, 0.f, 0.f, 0.f};
#pragma unroll
            for (int dr = 0; dr < KK; ++dr) {
                const __half* rp = &buf[cur][lrow - 2 + dr][hc - 4];
                uint2 q0 = *(const uint2*)(rp);        // halves hc-4..hc-1
                uint2 q1 = *(const uint2*)(rp + 4);    // hc  ..hc+3
                uint2 q2 = *(const uint2*)(rp + 8);    // hc+4..hc+7
#ifdef USE_FDOT2
                const unsigned u1 = q0.y, u2 = q1.x, u3 = q1.y,
                               u4 = q2.x, u5 = q2.y;
                const unsigned sh1 = (u1 >> 16) | (u2 << 16);
                const unsigned sh2 = (u2 >> 16) | (u3 << 16);
                const unsigned sh3 = (u3 >> 16) | (u4 << 16);
                const unsigned sh4 = (u4 >> 16) | (u5 << 16);
                acc[0] = fdot2f(Wp[0][dr][0], u1,  acc[0]);
                acc[0] = fdot2f(Wp[0][dr][1], u2,  acc[0]);
                acc[0] = fdot2f(Wp[0][dr][2], u3,  acc[0]);
                acc[1] = fdot2f(Wp[1][dr][0], sh1, acc[1]);
                acc[1] = fdot2f(Wp[1][dr][1], sh2, acc[1]);
                acc[1] = fdot2f(Wp[1][dr][2], sh3, acc[1]);
                acc[2] = fdot2f(Wp[2][dr][0], u2,  acc[2]);
                acc[2] = fdot2f(Wp[2][dr][1], u3,  acc[2]);
                acc[2] = fdot2f(Wp[2][dr][2], u4,  acc[2]);
                acc[3] = fdot2f(Wp[3][dr][0], sh2, acc[3]);
                acc[3] = fdot2f(Wp[3][dr][1], sh3, acc[3]);
                acc[3] = fdot2f(Wp[3][dr][2], sh4, acc[3]);
#else
                union { uint2 u2v; __half2 h[2]; } r0, r1, r2;
                r0.u2v = q0; r1.u2v = q1; r2.u2v = q2;
                float xs[12];
                float2 t2;
                t2 = __half22float2(r0.h[0]); xs[0]  = t2.x; xs[1]  = t2.y;
                t2 = __half22float2(r0.h[1]); xs[2]  = t2.x; xs[3]  = t2.y;
                t2 = __half22float2(r1.h[0]); xs[4]  = t2.x; xs[5]  = t2.y;
                t2 = __half22float2(r1.h[1]); xs[6]  = t2.x; xs[7]  = t2.y;
                t2 = __half22float2(r2.h[0]); xs[8]  = t2.x; xs[9]  = t2.y;
                t2 = __half22float2(r2.h[1]); xs[10] = t2.x; xs[11] = t2.y;
#pragma unroll
                for (int dc = 0; dc < KK; ++dc) {
                    const int t = dr * KK + dc;
                    float2 w01 = __half22float2(W[t][0]);
                    float2 w23 = __half22float2(W[t][1]);
                    acc[0] = fmaf(w01.x, xs[dc + 2], acc[0]);
                    acc[1] = fmaf(w01.y, xs[dc + 3], acc[1]);
                    acc[2] = fmaf(w23.x, xs[dc + 4], acc[2]);
                    acc[3] = fmaf(w23.y, xs[dc + 5], acc[3]);
                }
#endif
            }
            o[0] = acc[0] * iv.x; o[1] = acc[1] * iv.y;
            o[2] = acc[2] * iv.z; o[3] = acc[3] * iv.w;
        }
        if (j < KF - 1) {
            if (actj) {
                union { uint2 u; __half2 h[2]; } st;
                st.h[0] = __floats2half2_rn(o[0], o[1]);
                st.h[1] = __floats2half2_rn(o[2], o[3]);
                *(uint2*)&buf[cur ^ 1][lrow][hc] = st.u;
            }
            cur ^= 1;
            __syncthreads();
        }
    }

    // ---- write back tile px (exact after KF sub-iters) --------------------
    if ((unsigned)relrow < TTR && (unsigned)relc0 < TTC) {
        float* dst = xout + bHW + (size_t)grow * WW + gcol;
        *(float4*)dst = make_float4(o[0], o[1], o[2], o[3]);
    }
}

extern "C" void kernel_launch(void* const* d_in, const int* in_sizes, int n_in,
                              void* d_out, int out_size, void* d_ws, size_t ws_size,
                              hipStream_t stream)
{
    const float* img  = (const float*)d_in[0];
    const float* feat = (const float*)d_in[1];
    const float* mask = (const float*)d_in[2];
    float* out = (float*)d_out;

    // ws: [ guard 2KB | planes 12*NP halves (14.2MB) | invm NP f32 | xa | xb ]
    __half* planes = (__half*)d_ws + GUARDH;
    float* invmp = (float*)(planes + (size_t)12 * NP);
    float* xa = invmp + NP;
    float* xb = xa + NP + 64;

    prep_sym<<<PGRID, 256, 0, stream>>>(img, feat, mask, planes, invmp, xa);
    iter4<<<IGRID, NTH, 0, stream>>>(planes, invmp, xa, xb);   // 1-4
    iter4<<<IGRID, NTH, 0, stream>>>(planes, invmp, xb, xa);   // 5-8
    iter4<<<IGRID, NTH, 0, stream>>>(planes, invmp, xa, xb);   // 9-12
    iter4<<<IGRID, NTH, 0, stream>>>(planes, invmp, xb, xa);   // 13-16
    iter4<<<IGRID, NTH, 0, stream>>>(planes, invmp, xa, out);  // 17-20
}

// Round 16
// 126.237 us; speedup vs baseline: 1.0994x; 1.0994x over previous
//
#include <hip/hip_runtime.h>
#include <hip/hip_fp16.h>

#define BB 4
#define CC 3
#define HH 384
#define WW 384
#define HW (HH * WW)
#define NP (BB * HW)
#define KK 5
#define RR 2
#define K2 25
#define NITER 20
#define TT 48            // output tile; 384/48 = 8 tiles/dim
#define KF 4             // fused iterations per launch (5 x 4 = 20)
#define LR 68            // LDS rows: region 64 + 2+2 zero ring
#define RSTH 80          // LDS row stride in HALVES (160 B)
#define NTH 1024         // 64 rows x 16 chunks, 4 px/thread: exact region cover
#define IGRID 256        // 8*8 tiles * 4 batches = 1 block/CU
#define PGRID 1152
#define PCPX (PGRID / 8)
#define GUARDH 1024      // guard halves before planes (max back-reach 770)

static constexpr float INV_Z2 = 1.0f / (0.15f * 0.15f);

typedef _Float16 h2_t __attribute__((ext_vector_type(2)));

#if defined(__has_builtin)
#if __has_builtin(__builtin_amdgcn_fdot2)
#define USE_FDOT2 1
#endif
#endif

static __device__ __forceinline__ unsigned h2u(__half2 h) {
    union { __half2 h; unsigned u; } v; v.h = h; return v.u;
}
#ifdef USE_FDOT2
static __device__ __forceinline__ float fdot2f(unsigned w, unsigned x, float c) {
    union { unsigned u; h2_t h; } a, b; a.u = w; b.u = x;
    return __builtin_amdgcn_fdot2(a.h, b.h, c, false);
}
#endif

// ---------------------------------------------------------------------------
// R15 probe verdict: 2-blocks/CU at 1.5x redundancy = 138.8us (between
// pure-throughput 165 and pure-exposure 112) -> R14's geometry (K=4, T=48,
// 4px/thread, 16-wave, redundancy 1.78) is the family optimum: total iter
// work scales as (64/T)^2, launches as 20/K, with T+4K<=64 forced by the
// VGPR-capped 4px/thread. R16 = R14 geometry + half-precision x handoff
// between launches: x is already half inside LDS; moving the f32->half
// rounding to the producer (store half, load half) is BIT-IDENTICAL while
// halving inter-launch x traffic and deleting stage-side cvts. Final launch
// writes f32 `out` via `last` flag. prep stores x0 as half (same rounding).
// ---------------------------------------------------------------------------

// prep: 2 px/thread. a(p,q) exactly symmetric in fp; center tap exactly 1.
// Stores 12 lex-positive UNnormalized planes (fp16, OOB taps exactly 0),
// invm = mask/sumz (fp32), and x0 = feat*mask as HALF. Clamped float2
// windows; clamped values only feed predicated-to-0 taps.
__global__ __launch_bounds__(256) void prep_sym(
    const float* __restrict__ img, const float* __restrict__ feat,
    const float* __restrict__ mask, __half* __restrict__ planes,
    float* __restrict__ invm, __half* __restrict__ x0)
{
    int sbid = (blockIdx.x & 7) * PCPX + (blockIdx.x >> 3);  // XCD-chunked
    int gid = sbid * 256 + threadIdx.x;
    int p0 = gid * 2;
    int b   = p0 / HW;
    int rem = p0 - b * HW;          // even
    int h   = rem / WW;
    int wc  = rem - h * WW;

    const float* imgb = img + (size_t)b * CC * HW;
    const size_t bHW = (size_t)b * HW;

    float2 f  = *(const float2*)(feat + bHW + rem);
    float2 mk = *(const float2*)(mask + bHW + rem);
    *(__half2*)(x0 + bHW + rem) = __floats2half2_rn(f.x * mk.x, f.y * mk.y);

    float v[CC][2];
#pragma unroll
    for (int c = 0; c < CC; ++c) {
        float2 cv = *(const float2*)(imgb + c * HW + rem);
        v[c][0] = cv.x + 10.f;
        v[c][1] = cv.y + 10.f;
    }

    float sz[2] = {1e-10f, 1e-10f};
#pragma unroll
    for (int dr = 0; dr < KK; ++dr) {
        const int rr  = h + dr - RR;
        const bool rok = (unsigned)rr < HH;
        const int rrc = min(max(rr, 0), HH - 1);
        float xs[CC][6];
#pragma unroll
        for (int c = 0; c < CC; ++c) {
            const float* rowp = imgb + c * HW + rrc * WW;
            float2 A = *(const float2*)(rowp + max(wc - 2, 0));
            float2 Bv = *(const float2*)(rowp + wc);
            float2 Cv = *(const float2*)(rowp + min(wc + 2, WW - 2));
            xs[c][0] = A.x + 10.f;  xs[c][1] = A.y + 10.f;
            xs[c][2] = Bv.x + 10.f; xs[c][3] = Bv.y + 10.f;
            xs[c][4] = Cv.x + 10.f; xs[c][5] = Cv.y + 10.f;
        }
#pragma unroll
        for (int dc = 0; dc < KK; ++dc) {
            const int t = dr * KK + dc;
            float av[2];
#pragma unroll
            for (int s = 0; s < 2; ++s) {
                const int cc2 = wc + s + dc - RR;
                const bool ok = rok && ((unsigned)cc2 < WW);
                float d0 = xs[0][s + dc] - v[0][s];
                float d1 = xs[1][s + dc] - v[1][s];
                float d2 = xs[2][s + dc] - v[2][s];
                float e = d0 * d0 + d1 * d1 + d2 * d2;
                av[s] = ok ? __expf(-e * INV_Z2) : 0.f;
                sz[s] += av[s];
            }
            if (t >= 13) {
                __half2 hv = __floats2half2_rn(av[0], av[1]);
                *(__half2*)(planes + (size_t)(t - 13) * NP + bHW + rem) = hv;
            }
        }
    }
    float i0 = 1.f / sz[0], i1 = 1.f / sz[1];
    *(float2*)(invm + bHW + rem) = make_float2(mk.x * i0, mk.y * i1);
}

// ---------------------------------------------------------------------------
// One launch = KF=4 sub-iterations. 1024 thr x 4 px cover the 64x64 region
// exactly. W loaded once (own taps early-issued uint2, mirror taps shifted-
// read + NaN-safe select), packed for v_dot2_f32_f16. x ping-pongs as HALF
// in global; half LDS dbuf inside. Shrink-region: sub-iter j guards radius
// 6-2j. Last launch writes f32 out.
// ---------------------------------------------------------------------------
__global__ __launch_bounds__(NTH, 2) void iter4(
    const __half* __restrict__ planes, const float* __restrict__ invm,
    const __half* __restrict__ xin, __half* __restrict__ xout,
    float* __restrict__ outf, int last)
{
    __shared__ __half buf[2][LR][RSTH];   // 21.8 KB

    const int tid = threadIdx.x;
    const int lin = (blockIdx.x & 7) * (IGRID / 8) + (blockIdx.x >> 3);
    const int b  = lin >> 6;
    const int ty = (lin >> 3) & 7;
    const int tx = lin & 7;
    const int tr0 = ty * TT, tc0 = tx * TT;
    const size_t bHW = (size_t)b * HW;

    const int row    = tid >> 4;          // 0..63
    const int chunk  = tid & 15;          // 0..15
    const int relrow = row - 8;           // -8..55
    const int relc0  = chunk * 4 - 8;     // -8..52, multiple of 4
    const int grow = tr0 + relrow;
    const int gcol = tc0 + relc0;
    const bool inimg = ((unsigned)grow < HH) && ((unsigned)gcol <= (WW - 4));
    const int lrow = relrow + 10;         // 2..65
    const int hc   = relc0 + 12;          // 4..64 halves (mult of 4, 8B-align)

    // ---- early-issue independent global loads (latency hides under zero) --
    uint2 own[12];
    uint2 hx = make_uint2(0u, 0u);        // 4 half x-values
    float4 iv = make_float4(0.f, 0.f, 0.f, 0.f);
    const __half* plb = planes + bHW + (size_t)grow * WW + gcol;
    if (inimg) {
        const size_t off = bHW + (size_t)grow * WW + gcol;
        hx = *(const uint2*)(xin + off);
        iv = *(const float4*)(invm + off);
#pragma unroll
        for (int u = 13; u < K2; ++u)
            own[u - 13] = *(const uint2*)(plb + (size_t)(u - 13) * NP);
    }

    // ---- zero both buffers (ring cells never rewritten) -------------------
    for (int i = tid; i < LR * RSTH; i += NTH)
        ((unsigned*)buf)[i] = 0u;
    __syncthreads();

    // stage own x (already half; no cvt)
    *(uint2*)&buf[0][lrow][hc] = hx;

    // ---- mirror loads + W build (overlaps the barrier) --------------------
    __half2 W[K2][2];
    const __half hz = __float2half(0.f);
    if (inimg) {
        W[12][0] = __floats2half2_rn(1.f, 1.f);
        W[12][1] = __floats2half2_rn(1.f, 1.f);
#pragma unroll
        for (int u = 13; u < K2; ++u) {
            const int dur = u / KK - RR;     // 0..2
            const int duc = u % KK - RR;     // -2..2
            const __half* pl = plb + (size_t)(u - 13) * NP;
            union { uint2 u2; __half2 h[2]; } ow;
            ow.u2 = own[u - 13];
            W[u][0] = ow.h[0];
            W[u][1] = ow.h[1];
            const int shift = -(dur * WW + duc);
            const bool okr = (dur == 0) || (grow >= dur);
            __half m[4];
            if ((u % KK) % 2 == 0) {         // duc even: 4B-aligned pair loads
                union { unsigned u32; __half h[2]; } a0, a1;
                a0.u32 = *(const unsigned*)(pl + shift);
                a1.u32 = *(const unsigned*)(pl + shift + 2);
                m[0] = a0.h[0]; m[1] = a0.h[1];
                m[2] = a1.h[0]; m[3] = a1.h[1];
            } else {                          // duc odd: scalar halves
                m[0] = pl[shift + 0]; m[1] = pl[shift + 1];
                m[2] = pl[shift + 2]; m[3] = pl[shift + 3];
            }
#pragma unroll
            for (int k = 0; k < 4; ++k)
                if (!(okr && (unsigned)(gcol + k - duc) < WW)) m[k] = hz;
            W[24 - u][0] = __halves2half2(m[0], m[1]);
            W[24 - u][1] = __halves2half2(m[2], m[3]);
        }
    } else {
#pragma unroll
        for (int t = 0; t < K2; ++t) {
            W[t][0] = __halves2half2(hz, hz);
            W[t][1] = __halves2half2(hz, hz);
        }
    }

#ifdef USE_FDOT2
    // ---- pack W into tap-pair u32s: Wp[px][dr][{dc01,dc23,dc4+zero}] ------
    unsigned Wp[4][KK][3];
#pragma unroll
    for (int dr = 0; dr < KK; ++dr) {
#pragma unroll
        for (int pc = 0; pc < 2; ++pc) {
            const int t0 = dr * KK + 2 * pc;
            unsigned a0 = h2u(W[t0][0]),     b0 = h2u(W[t0][1]);
            unsigned a1 = h2u(W[t0 + 1][0]), b1 = h2u(W[t0 + 1][1]);
            Wp[0][dr][pc] = (a0 & 0xFFFFu) | (a1 << 16);
            Wp[1][dr][pc] = (a0 >> 16)     | (a1 & 0xFFFF0000u);
            Wp[2][dr][pc] = (b0 & 0xFFFFu) | (b1 << 16);
            Wp[3][dr][pc] = (b0 >> 16)     | (b1 & 0xFFFF0000u);
        }
        unsigned a = h2u(W[dr * KK + 4][0]), bb = h2u(W[dr * KK + 4][1]);
        Wp[0][dr][2] = a & 0xFFFFu;
        Wp[1][dr][2] = a >> 16;
        Wp[2][dr][2] = bb & 0xFFFFu;
        Wp[3][dr][2] = bb >> 16;
    }
#endif
    __syncthreads();   // buf[0] fully staged

    // ---- KF sub-iterations, shrink-region guarded -------------------------
    int cur = 0;
    float o[4] = {0.f, 0.f, 0.f, 0.f};
#pragma unroll 1
    for (int j = 0; j < KF; ++j) {
        const int rj = 2 * (KF - 1 - j);            // 6,4,2,0
        const bool actj = (relrow >= -rj) && (relrow < TT + rj) &&
                          (relc0 + 3 >= -rj) && (relc0 < TT + rj);
        if (actj) {
            float acc[4] = {0.f, 0.f, 0.f, 0.f};
#pragma unroll
            for (int dr = 0; dr < KK; ++dr) {
                const __half* rp = &buf[cur][lrow - 2 + dr][hc - 4];
                uint2 q0 = *(const uint2*)(rp);        // halves hc-4..hc-1
                uint2 q1 = *(const uint2*)(rp + 4);    // hc  ..hc+3
                uint2 q2 = *(const uint2*)(rp + 8);    // hc+4..hc+7
#ifdef USE_FDOT2
                const unsigned u1 = q0.y, u2 = q1.x, u3 = q1.y,
                               u4 = q2.x, u5 = q2.y;
                const unsigned sh1 = (u1 >> 16) | (u2 << 16);
                const unsigned sh2 = (u2 >> 16) | (u3 << 16);
                const unsigned sh3 = (u3 >> 16) | (u4 << 16);
                const unsigned sh4 = (u4 >> 16) | (u5 << 16);
                acc[0] = fdot2f(Wp[0][dr][0], u1,  acc[0]);
                acc[0] = fdot2f(Wp[0][dr][1], u2,  acc[0]);
                acc[0] = fdot2f(Wp[0][dr][2], u3,  acc[0]);
                acc[1] = fdot2f(Wp[1][dr][0], sh1, acc[1]);
                acc[1] = fdot2f(Wp[1][dr][1], sh2, acc[1]);
                acc[1] = fdot2f(Wp[1][dr][2], sh3, acc[1]);
                acc[2] = fdot2f(Wp[2][dr][0], u2,  acc[2]);
                acc[2] = fdot2f(Wp[2][dr][1], u3,  acc[2]);
                acc[2] = fdot2f(Wp[2][dr][2], u4,  acc[2]);
                acc[3] = fdot2f(Wp[3][dr][0], sh2, acc[3]);
                acc[3] = fdot2f(Wp[3][dr][1], sh3, acc[3]);
                acc[3] = fdot2f(Wp[3][dr][2], sh4, acc[3]);
#else
                union { uint2 u2v; __half2 h[2]; } r0, r1, r2;
                r0.u2v = q0; r1.u2v = q1; r2.u2v = q2;
                float xs[12];
                float2 t2;
                t2 = __half22float2(r0.h[0]); xs[0]  = t2.x; xs[1]  = t2.y;
                t2 = __half22float2(r0.h[1]); xs[2]  = t2.x; xs[3]  = t2.y;
                t2 = __half22float2(r1.h[0]); xs[4]  = t2.x; xs[5]  = t2.y;
                t2 = __half22float2(r1.h[1]); xs[6]  = t2.x; xs[7]  = t2.y;
                t2 = __half22float2(r2.h[0]); xs[8]  = t2.x; xs[9]  = t2.y;
                t2 = __half22float2(r2.h[1]); xs[10] = t2.x; xs[11] = t2.y;
#pragma unroll
                for (int dc = 0; dc < KK; ++dc) {
                    const int t = dr * KK + dc;
                    float2 w01 = __half22float2(W[t][0]);
                    float2 w23 = __half22float2(W[t][1]);
                    acc[0] = fmaf(w01.x, xs[dc + 2], acc[0]);
                    acc[1] = fmaf(w01.y, xs[dc + 3], acc[1]);
                    acc[2] = fmaf(w23.x, xs[dc + 4], acc[2]);
                    acc[3] = fmaf(w23.y, xs[dc + 5], acc[3]);
                }
#endif
            }
            o[0] = acc[0] * iv.x; o[1] = acc[1] * iv.y;
            o[2] = acc[2] * iv.z; o[3] = acc[3] * iv.w;
        }
        if (j < KF - 1) {
            if (actj) {
                union { uint2 u; __half2 h[2]; } st;
                st.h[0] = __floats2half2_rn(o[0], o[1]);
                st.h[1] = __floats2half2_rn(o[2], o[3]);
                *(uint2*)&buf[cur ^ 1][lrow][hc] = st.u;
            }
            cur ^= 1;
            __syncthreads();
        }
    }

    // ---- write back tile px (exact after KF sub-iters; always in-image) ---
    if ((unsigned)relrow < TT && (unsigned)relc0 < TT) {
        const size_t off = bHW + (size_t)grow * WW + gcol;
        if (last) {
            *(float4*)(outf + off) = make_float4(o[0], o[1], o[2], o[3]);
        } else {
            union { uint2 u; __half2 h[2]; } st;
            st.h[0] = __floats2half2_rn(o[0], o[1]);
            st.h[1] = __floats2half2_rn(o[2], o[3]);
            *(uint2*)(xout + off) = st.u;
        }
    }
}

extern "C" void kernel_launch(void* const* d_in, const int* in_sizes, int n_in,
                              void* d_out, int out_size, void* d_ws, size_t ws_size,
                              hipStream_t stream)
{
    const float* img  = (const float*)d_in[0];
    const float* feat = (const float*)d_in[1];
    const float* mask = (const float*)d_in[2];
    float* out = (float*)d_out;

    // ws: [ guard 2KB | planes 12*NP halves (14.2MB) | invm NP f32
    //       | xa NP halves | pad | xb NP halves ]
    __half* planes = (__half*)d_ws + GUARDH;
    float* invmp = (float*)(planes + (size_t)12 * NP);
    __half* xa = (__half*)(invmp + NP);
    __half* xb = xa + NP + 64;

    prep_sym<<<PGRID, 256, 0, stream>>>(img, feat, mask, planes, invmp, xa);
    iter4<<<IGRID, NTH, 0, stream>>>(planes, invmp, xa, xb, out, 0); // 1-4
    iter4<<<IGRID, NTH, 0, stream>>>(planes, invmp, xb, xa, out, 0); // 5-8
    iter4<<<IGRID, NTH, 0, stream>>>(planes, invmp, xa, xb, out, 0); // 9-12
    iter4<<<IGRID, NTH, 0, stream>>>(planes, invmp, xb, xa, out, 0); // 13-16
    iter4<<<IGRID, NTH, 0, stream>>>(planes, invmp, xa, xb, out, 1); // 17-20
}